// Round 1
// 8127.760 us; speedup vs baseline: 1.2911x; 1.2911x over previous
//
#include <hip/hip_runtime.h>
#include <hip/hip_bf16.h>
#include <cstdint>
#include <cstddef>

typedef __attribute__((ext_vector_type(8))) __bf16 bf16x8;
typedef __attribute__((ext_vector_type(4))) float f32x4;

__device__ __forceinline__ unsigned cvt_pk(float x, float y) {
    __hip_bfloat162 h = __float22bfloat162_rn(make_float2(x, y));
    return *reinterpret_cast<unsigned*>(&h);
}

// ---------------- block reduction (256 threads = 4 waves) ----------------
__device__ __forceinline__ float block_sum(float v, float* sm) {
    __syncthreads();
    #pragma unroll
    for (int off = 32; off > 0; off >>= 1) v += __shfl_down(v, off, 64);
    int w = threadIdx.x >> 6;
    if ((threadIdx.x & 63) == 0) sm[w] = v;
    __syncthreads();
    return sm[0] + sm[1] + sm[2] + sm[3];
}

// ---------------- LayerNorm: one block per row, E=1024 ----------------
__global__ __launch_bounds__(256) void ln_kernel(const float* __restrict__ x,
                                                 const float* __restrict__ g,
                                                 const float* __restrict__ b,
                                                 float* __restrict__ out) {
    __shared__ float sm[4];
    const int E = 1024;
    size_t row = blockIdx.x;
    const float* xr = x + row * E;
    float v[4];
    float s = 0.f;
    #pragma unroll
    for (int j = 0; j < 4; j++) { v[j] = xr[threadIdx.x + 256*j]; s += v[j]; }
    s = block_sum(s, sm);
    float mean = s * (1.f/1024.f);
    float vs = 0.f;
    #pragma unroll
    for (int j = 0; j < 4; j++) { float d = v[j] - mean; vs += d*d; }
    vs = block_sum(vs, sm);
    float inv = rsqrtf(vs * (1.f/1024.f) + 1e-5f);
    float* orow = out + row * E;
    #pragma unroll
    for (int j = 0; j < 4; j++) {
        int i = threadIdx.x + 256*j;
        orow[i] = (v[j]-mean)*inv*g[i] + b[i];
    }
}

// ---------------- MFMA GEMM: C[M,N] = A[M,K] @ W[N,K]^T ------------------
// fp32 global operands, converted to bf16 during LDS staging; fp32 accumulate.
// MODE 0: C = acc (+bias if non-null)
// MODE 1: C = relu(acc)^2
// MODE 2: C += sigmoid(R) * acc      (ChannelMix tail)
// MODE 3: C += acc                   (residual add)
template<int MODE>
__global__ __launch_bounds__(256) void gemm_nt(const float* __restrict__ A,
                                               const float* __restrict__ W,
                                               const float* __restrict__ bias,
                                               const float* __restrict__ R,
                                               float* __restrict__ C,
                                               int M, int N, int K) {
    constexpr int BM = 128, BN = 128, BK = 32;
    constexpr int PAD = 40;                       // LDS row stride in bf16 elems
    __shared__ unsigned short As[BM * PAD];       // 10240 B
    __shared__ unsigned short Ws[BN * PAD];       // 10240 B
    const int tid  = threadIdx.x;
    const int wave = tid >> 6, lane = tid & 63;
    const int waveM = wave >> 1, waveN = wave & 1;     // 2x2 wave grid
    const int r16 = lane & 15, quad = lane >> 4;
    const int m0 = blockIdx.y * BM, n0 = blockIdx.x * BN;

    f32x4 acc[4][4] = {};   // [mt][nt], 64 VGPR/AGPR

    for (int k0 = 0; k0 < K; k0 += BK) {
        // ---- stage A tile: 128 rows x 32 fp32 -> bf16 LDS ----
        #pragma unroll
        for (int i = 0; i < 4; i++) {
            int f = i * 256 + tid;            // 0..1023 float4 chunks
            int row = f >> 3, c4 = f & 7;     // 8 float4 per row
            float4 av = *reinterpret_cast<const float4*>(&A[(size_t)(m0 + row) * K + k0 + c4 * 4]);
            unsigned lo = cvt_pk(av.x, av.y), hi = cvt_pk(av.z, av.w);
            *reinterpret_cast<uint2*>(&As[row * PAD + c4 * 4]) = make_uint2(lo, hi);
        }
        // ---- stage W tile ----
        #pragma unroll
        for (int i = 0; i < 4; i++) {
            int f = i * 256 + tid;
            int row = f >> 3, c4 = f & 7;
            float4 wv = *reinterpret_cast<const float4*>(&W[(size_t)(n0 + row) * K + k0 + c4 * 4]);
            unsigned lo = cvt_pk(wv.x, wv.y), hi = cvt_pk(wv.z, wv.w);
            *reinterpret_cast<uint2*>(&Ws[row * PAD + c4 * 4]) = make_uint2(lo, hi);
        }
        __syncthreads();

        // ---- fragments: A[m=lane&15][k=quad*8+j], B[n=lane&15][k=quad*8+j] ----
        bf16x8 af[4], bfr[4];
        #pragma unroll
        for (int mt = 0; mt < 4; mt++)
            af[mt] = *reinterpret_cast<const bf16x8*>(&As[(waveM * 64 + mt * 16 + r16) * PAD + quad * 8]);
        #pragma unroll
        for (int nt = 0; nt < 4; nt++)
            bfr[nt] = *reinterpret_cast<const bf16x8*>(&Ws[(waveN * 64 + nt * 16 + r16) * PAD + quad * 8]);

        #pragma unroll
        for (int mt = 0; mt < 4; mt++)
            #pragma unroll
            for (int nt = 0; nt < 4; nt++)
                acc[mt][nt] = __builtin_amdgcn_mfma_f32_16x16x32_bf16(af[mt], bfr[nt], acc[mt][nt], 0, 0, 0);
        __syncthreads();
    }

    // ---- epilogue: D[row=quad*4+r][col=lane&15] ----
    #pragma unroll
    for (int mt = 0; mt < 4; mt++) {
        #pragma unroll
        for (int r = 0; r < 4; r++) {
            int m = m0 + waveM * 64 + mt * 16 + quad * 4 + r;
            #pragma unroll
            for (int nt = 0; nt < 4; nt++) {
                int n = n0 + waveN * 64 + nt * 16 + r16;
                size_t off = (size_t)m * N + n;
                float v = acc[mt][nt][r];
                if (MODE == 0) {
                    if (bias) v += bias[n];
                    C[off] = v;
                } else if (MODE == 1) {
                    v = fmaxf(v, 0.f);
                    C[off] = v * v;
                } else if (MODE == 2) {
                    C[off] += v / (1.f + expf(-R[off]));
                } else {
                    C[off] += v;
                }
            }
        }
    }
}

// ---------------- WKV recurrence: one thread per (b,e) channel -------------
// v == r in this model; sigmoid(r)*wkv is folded into the y write.
//
// R0 change: this kernel runs at 0.73% occupancy (4096 threads total, 64
// waves on 256 CUs) so NO TLP exists to hide memory latency. The old code
// prefetched only 1 step ahead (~150 cyc of slack) against ~400-900 cyc
// L2/LLC/HBM load latency -> 720 cyc/step observed. Fix:
//  (a) software prefetch ring, depth PF=8: loads for steps t+8..t+15 are
//      issued before computing steps t..t+7 (~1000 cyc slack).
//  (b) cut per-step VALU: one v_rcp_f32 replaces both divides
//      (wkv-div and sigmoid-div merged), __expf (v_exp_f32) for all exps.
//      Tolerance is absmax 0.03125; rcp/fast-exp rel err ~1e-6.
__device__ __forceinline__ void wkv_step(float kt, float vt, float w, float u,
                                         float& aa, float& bb, float& pp,
                                         float& yt) {
    float ww = u + kt;
    float p  = fmaxf(pp, ww);
    float e1 = __expf(pp - p), e2 = __expf(ww - p);
    float num = fmaf(e1, aa, e2 * vt);
    float den = fmaf(e1, bb, e2);
    float sig = 1.f + __expf(-vt);                 // 1/sigmoid(r)
    yt = num * __builtin_amdgcn_rcpf(den * sig);   // wkv * sigmoid(r)
    float ww2 = pp + w;
    float p2  = fmaxf(ww2, kt);
    float e1b = __expf(ww2 - p2), e2b = __expf(kt - p2);
    aa = fmaf(e1b, aa, e2b * vt);
    bb = fmaf(e1b, bb, e2b);
    pp = p2;
}

__global__ __launch_bounds__(64) void wkv_kernel(const float* __restrict__ k,
                                                 const float* __restrict__ v,
                                                 const float* __restrict__ decay,
                                                 const float* __restrict__ first,
                                                 float* __restrict__ y) {
    const int T = 1024, E = 1024;
    constexpr int PF = 8;                       // prefetch depth (time steps)
    int idx = blockIdx.x * 64 + threadIdx.x;    // 0..4095 = B*E
    int b = idx >> 10, e = idx & 1023;
    float w = -expf(decay[e]);
    float u = first[e];
    float aa = 0.f, bb = 0.f, pp = -1e38f;
    const float* kp = k + (size_t)b*T*E + e;
    const float* vp = v + (size_t)b*T*E + e;
    float* yp = y + (size_t)b*T*E + e;

    float kbuf[PF], vbuf[PF];
    #pragma unroll
    for (int j = 0; j < PF; j++) {
        kbuf[j] = kp[(size_t)j * E];
        vbuf[j] = vp[(size_t)j * E];
    }

    for (int t0 = 0; t0 < T - PF; t0 += PF) {
        // issue next chunk's loads before touching this chunk's values
        float kn[PF], vn[PF];
        #pragma unroll
        for (int j = 0; j < PF; j++) {
            kn[j] = kp[(size_t)(t0 + PF + j) * E];
            vn[j] = vp[(size_t)(t0 + PF + j) * E];
        }
        #pragma unroll
        for (int j = 0; j < PF; j++) {
            float yt;
            wkv_step(kbuf[j], vbuf[j], w, u, aa, bb, pp, yt);
            yp[(size_t)(t0 + j) * E] = yt;
        }
        #pragma unroll
        for (int j = 0; j < PF; j++) { kbuf[j] = kn[j]; vbuf[j] = vn[j]; }
    }
    // final chunk (t = T-PF .. T-1), already in kbuf/vbuf
    #pragma unroll
    for (int j = 0; j < PF; j++) {
        float yt;
        wkv_step(kbuf[j], vbuf[j], w, u, aa, bb, pp, yt);
        yp[(size_t)(T - PF + j) * E] = yt;
    }
}

extern "C" void kernel_launch(void* const* d_in, const int* in_sizes, int n_in,
                              void* d_out, int out_size, void* d_ws, size_t ws_size,
                              hipStream_t stream) {
    const float* inputs   = (const float*)d_in[0];
    const float* W_in     = (const float*)d_in[1];
    const float* b_in     = (const float*)d_in[2];
    const float* l0_ln0_g = (const float*)d_in[3];
    const float* l0_ln0_b = (const float*)d_in[4];
    const float* l0_ln1_g = (const float*)d_in[5];
    const float* l0_ln1_b = (const float*)d_in[6];
    const float* l0_ln2_g = (const float*)d_in[7];
    const float* l0_ln2_b = (const float*)d_in[8];
    const float* l0_cm_k  = (const float*)d_in[9];
    const float* l0_cm_v  = (const float*)d_in[10];
    const float* l0_cm_r  = (const float*)d_in[11];
    const float* l0_ff_k  = (const float*)d_in[12];
    const float* l0_ff_v  = (const float*)d_in[13];
    const float* l0_ff_r  = (const float*)d_in[14];
    const float* tm_k     = (const float*)d_in[15];
    const float* tm_r     = (const float*)d_in[16];
    const float* tm_o     = (const float*)d_in[17];
    const float* tm_decay = (const float*)d_in[18];
    const float* tm_first = (const float*)d_in[19];
    const float* ln1_g    = (const float*)d_in[20];
    const float* ln1_b    = (const float*)d_in[21];
    const float* ln2_g    = (const float*)d_in[22];
    const float* ln2_b    = (const float*)d_in[23];
    const float* ff_k     = (const float*)d_in[24];
    const float* ff_v     = (const float*)d_in[25];
    const float* ff_r     = (const float*)d_in[26];
    const float* out_g    = (const float*)d_in[27];
    const float* out_b    = (const float*)d_in[28];

    const int Mrows = 4096, E = 1024, E4 = 4096, D = 512, L1 = 11;
    float* ws = (float*)d_ws;
    const size_t S = (size_t)Mrows * E;
    float* res = ws;          // [M,E]
    float* xn  = ws + 1*S;    // [M,E]
    float* kb  = ws + 2*S;    // [M,E]
    float* rb  = ws + 3*S;    // [M,E]
    float* yb  = ws + 4*S;    // [M,E]
    float* hb  = ws + 5*S;    // [M,4E]  (4*S floats)
    (void)ws_size; (void)in_sizes; (void)n_in; (void)out_size;

    dim3 blk(256);
    dim3 gE (E /128, Mrows/128);   // (8,32)
    dim3 gE4(E4/128, Mrows/128);   // (32,32)

    // x = inputs @ W_in.T + b_in  -> kb
    gemm_nt<0><<<gE, blk, 0, stream>>>(inputs, W_in, b_in, nullptr, kb, Mrows, E, D);
    // res = LN(x, ln0)
    ln_kernel<<<Mrows, blk, 0, stream>>>(kb, l0_ln0_g, l0_ln0_b, res);
    // res += CM(LN(res, ln1); cm_k, cm_v, cm_r)
    ln_kernel<<<Mrows, blk, 0, stream>>>(res, l0_ln1_g, l0_ln1_b, xn);
    gemm_nt<1><<<gE4, blk, 0, stream>>>(xn, l0_cm_k, nullptr, nullptr, hb, Mrows, E4, E);
    gemm_nt<0><<<gE,  blk, 0, stream>>>(xn, l0_cm_r, nullptr, nullptr, rb, Mrows, E, E);
    gemm_nt<2><<<gE,  blk, 0, stream>>>(hb, l0_cm_v, nullptr, rb, res, Mrows, E, E4);
    // res += CM(LN(res, ln2); ff_k, ff_v, ff_r)   [layer-0 ffn]
    ln_kernel<<<Mrows, blk, 0, stream>>>(res, l0_ln2_g, l0_ln2_b, xn);
    gemm_nt<1><<<gE4, blk, 0, stream>>>(xn, l0_ff_k, nullptr, nullptr, hb, Mrows, E4, E);
    gemm_nt<0><<<gE,  blk, 0, stream>>>(xn, l0_ff_r, nullptr, nullptr, rb, Mrows, E, E);
    gemm_nt<2><<<gE,  blk, 0, stream>>>(hb, l0_ff_v, nullptr, rb, res, Mrows, E, E4);

    for (int l = 0; l < L1; l++) {
        const float* Wk = tm_k + (size_t)l*E*E;
        const float* Wr = tm_r + (size_t)l*E*E;
        const float* Wo = tm_o + (size_t)l*E*E;
        // xn = LN(res, ln1[l])
        ln_kernel<<<Mrows, blk, 0, stream>>>(res, ln1_g + (size_t)l*E, ln1_b + (size_t)l*E, xn);
        // k = xn @ Wk.T ; r = xn @ Wr.T
        gemm_nt<0><<<gE, blk, 0, stream>>>(xn, Wk, nullptr, nullptr, kb, Mrows, E, E);
        gemm_nt<0><<<gE, blk, 0, stream>>>(xn, Wr, nullptr, nullptr, rb, Mrows, E, E);
        // y = sigmoid(r) * wkv(-exp(decay), first, k, r)
        wkv_kernel<<<64, 64, 0, stream>>>(kb, rb, tm_decay + (size_t)l*E, tm_first + (size_t)l*E, yb);
        // res += y @ Wo.T
        gemm_nt<3><<<gE, blk, 0, stream>>>(yb, Wo, nullptr, nullptr, res, Mrows, E, E);
        // res += CM(LN(res, ln2[l]); ff_k[l], ff_v[l], ff_r[l])
        ln_kernel<<<Mrows, blk, 0, stream>>>(res, ln2_g + (size_t)l*E, ln2_b + (size_t)l*E, xn);
        gemm_nt<1><<<gE4, blk, 0, stream>>>(xn, ff_k + (size_t)l*E4*E, nullptr, nullptr, hb, Mrows, E4, E);
        gemm_nt<0><<<gE,  blk, 0, stream>>>(xn, ff_r + (size_t)l*E*E,  nullptr, nullptr, rb, Mrows, E, E);
        gemm_nt<2><<<gE,  blk, 0, stream>>>(hb, ff_v + (size_t)l*E*E4, nullptr, rb, res, Mrows, E, E4);
    }

    // out = LN(res, out_g, out_b)
    ln_kernel<<<Mrows, blk, 0, stream>>>(res, out_g, out_b, (float*)d_out);
}

// Round 2
// 4866.783 us; speedup vs baseline: 2.1562x; 1.6700x over previous
//
#include <hip/hip_runtime.h>
#include <hip/hip_bf16.h>
#include <cstdint>
#include <cstddef>

typedef __attribute__((ext_vector_type(8))) __bf16 bf16x8;
typedef __attribute__((ext_vector_type(4))) float f32x4;
typedef unsigned short ushort;

__device__ __forceinline__ unsigned cvt_pk(float x, float y) {
    __hip_bfloat162 h = __float22bfloat162_rn(make_float2(x, y));
    return *reinterpret_cast<unsigned*>(&h);
}
__device__ __forceinline__ ushort bf16u(float x) {
    __hip_bfloat16 h = __float2bfloat16(x);
    return *reinterpret_cast<ushort*>(&h);
}

// async global->LDS, 16B per lane (dest must be wave-uniform base + lane*16)
__device__ __forceinline__ void gl_lds16(const ushort* g, ushort* l) {
    __builtin_amdgcn_global_load_lds(
        (const __attribute__((address_space(1))) unsigned int*)g,
        (__attribute__((address_space(3))) unsigned int*)l,
        16, 0, 0);
}

// ---------------- fp32 -> bf16 convert (vectorized, grid-stride-free) -----
__global__ __launch_bounds__(256) void cvt_kernel(const float* __restrict__ x,
                                                  ushort* __restrict__ o, int n4) {
    int i = blockIdx.x * 256 + threadIdx.x;
    if (i < n4) {
        float4 v = reinterpret_cast<const float4*>(x)[i];
        unsigned lo = cvt_pk(v.x, v.y), hi = cvt_pk(v.z, v.w);
        reinterpret_cast<uint2*>(o)[i] = make_uint2(lo, hi);
    }
}

// ---------------- block reduction (256 threads = 4 waves) ----------------
__device__ __forceinline__ float block_sum(float v, float* sm) {
    __syncthreads();
    #pragma unroll
    for (int off = 32; off > 0; off >>= 1) v += __shfl_down(v, off, 64);
    int w = threadIdx.x >> 6;
    if ((threadIdx.x & 63) == 0) sm[w] = v;
    __syncthreads();
    return sm[0] + sm[1] + sm[2] + sm[3];
}

// ---------------- LayerNorm: one block per row, E=1024 ----------------
// OT = float (residual / final out) or ushort (bf16 activation for GEMM A)
template<typename OT>
__global__ __launch_bounds__(256) void ln_kernel(const float* __restrict__ x,
                                                 const float* __restrict__ g,
                                                 const float* __restrict__ b,
                                                 OT* __restrict__ out) {
    __shared__ float sm[4];
    const int E = 1024;
    size_t row = blockIdx.x;
    const float* xr = x + row * E;
    float v[4];
    float s = 0.f;
    #pragma unroll
    for (int j = 0; j < 4; j++) { v[j] = xr[threadIdx.x + 256*j]; s += v[j]; }
    s = block_sum(s, sm);
    float mean = s * (1.f/1024.f);
    float vs = 0.f;
    #pragma unroll
    for (int j = 0; j < 4; j++) { float d = v[j] - mean; vs += d*d; }
    vs = block_sum(vs, sm);
    float inv = rsqrtf(vs * (1.f/1024.f) + 1e-5f);
    OT* orow = out + row * E;
    #pragma unroll
    for (int j = 0; j < 4; j++) {
        int i = threadIdx.x + 256*j;
        float r = (v[j]-mean)*inv*g[i] + b[i];
        if constexpr (sizeof(OT) == 4) orow[i] = r;
        else                           orow[i] = bf16u(r);
    }
}

// ---------------- MFMA GEMM (all-bf16 operands): C = A[M,K] @ W[N,K]^T ----
// m97 structure: 128x128 tile, BK=64, global_load_lds width 16, XOR-swizzled
// both-sides LDS layout (rule #21): linear LDS dest, source chunk c = pc^(row&7),
// ds_read applies the same XOR. Row stride 128B would otherwise be a 16-way
// bank conflict on ds_read_b128.
// MODE 0: C(f32) = acc (+bias)     MODE 1: C(bf16) = relu(acc)^2
// MODE 2: C(f32) += sigmoid(R)*acc MODE 3: C(f32) += acc
template<int MODE>
__global__ __launch_bounds__(256) void gemm_bt(const ushort* __restrict__ A,
                                               const ushort* __restrict__ W,
                                               const float* __restrict__ bias,
                                               const float* __restrict__ R,
                                               void* __restrict__ Cv,
                                               int M, int N, int K) {
    constexpr int BM = 128, BN = 128, BK = 64;
    __shared__ ushort As[BM * BK];   // 16 KB, linear [row][64]
    __shared__ ushort Bs[BN * BK];   // 16 KB
    const int tid  = threadIdx.x;
    const int wave = tid >> 6, lane = tid & 63;
    const int waveM = wave >> 1, waveN = wave & 1;     // 2x2 wave grid
    const int r16 = lane & 15, quad = lane >> 4;
    const int m0 = blockIdx.y * BM, n0 = blockIdx.x * BN;

    f32x4 acc[4][4] = {};   // 64 VGPR

    for (int k0 = 0; k0 < K; k0 += BK) {
        // stage A tile: 128 rows x 64 bf16. chunk fc covers 8 bf16 (16B).
        #pragma unroll
        for (int i = 0; i < 4; i++) {
            int fc = i * 256 + tid;           // 0..1023
            int row = fc >> 3, pc = fc & 7;
            int c = pc ^ (row & 7);           // inverse-swizzled source chunk
            gl_lds16(&A[(size_t)(m0 + row) * K + k0 + c * 8], &As[fc * 8]);
        }
        #pragma unroll
        for (int i = 0; i < 4; i++) {
            int fc = i * 256 + tid;
            int row = fc >> 3, pc = fc & 7;
            int c = pc ^ (row & 7);
            gl_lds16(&W[(size_t)(n0 + row) * K + k0 + c * 8], &Bs[fc * 8]);
        }
        __syncthreads();   // compiler emits vmcnt(0) drain here (m97 structure)

        // fragments: A[m=r16][k=kk*32+quad*8+j]; swizzled chunk read
        bf16x8 af[2][4], bfm[2][4];
        #pragma unroll
        for (int kk = 0; kk < 2; kk++) {
            #pragma unroll
            for (int mt = 0; mt < 4; mt++) {
                int row = waveM * 64 + mt * 16 + r16;
                int ch = (kk * 4 + quad) ^ (row & 7);
                af[kk][mt] = *reinterpret_cast<const bf16x8*>(&As[row * BK + ch * 8]);
            }
            #pragma unroll
            for (int nt = 0; nt < 4; nt++) {
                int row = waveN * 64 + nt * 16 + r16;
                int ch = (kk * 4 + quad) ^ (row & 7);
                bfm[kk][nt] = *reinterpret_cast<const bf16x8*>(&Bs[row * BK + ch * 8]);
            }
        }
        #pragma unroll
        for (int kk = 0; kk < 2; kk++)
            #pragma unroll
            for (int mt = 0; mt < 4; mt++)
                #pragma unroll
                for (int nt = 0; nt < 4; nt++)
                    acc[mt][nt] = __builtin_amdgcn_mfma_f32_16x16x32_bf16(
                        af[kk][mt], bfm[kk][nt], acc[mt][nt], 0, 0, 0);
        __syncthreads();
    }

    // epilogue: D[row=quad*4+r][col=r16]
    #pragma unroll
    for (int mt = 0; mt < 4; mt++) {
        #pragma unroll
        for (int r = 0; r < 4; r++) {
            int m = m0 + waveM * 64 + mt * 16 + quad * 4 + r;
            #pragma unroll
            for (int nt = 0; nt < 4; nt++) {
                int n = n0 + waveN * 64 + nt * 16 + r16;
                size_t off = (size_t)m * N + n;
                float v = acc[mt][nt][r];
                if constexpr (MODE == 0) {
                    float* C = (float*)Cv;
                    if (bias) v += bias[n];
                    C[off] = v;
                } else if constexpr (MODE == 1) {
                    ushort* C = (ushort*)Cv;
                    v = fmaxf(v, 0.f);
                    C[off] = bf16u(v * v);
                } else if constexpr (MODE == 2) {
                    float* C = (float*)Cv;
                    C[off] += v / (1.f + expf(-R[off]));
                } else {
                    float* C = (float*)Cv;
                    C[off] += v;
                }
            }
        }
    }
}

// ---------------- WKV recurrence: one thread per (b,e) channel -------------
// Latency-bound at 0.73% occupancy: PF=8 software prefetch ring (R0, verified
// 307->~80us). Writes bf16 y directly (feeds the Wo GEMM).
__device__ __forceinline__ void wkv_step(float kt, float vt, float w, float u,
                                         float& aa, float& bb, float& pp,
                                         float& yt) {
    float ww = u + kt;
    float p  = fmaxf(pp, ww);
    float e1 = __expf(pp - p), e2 = __expf(ww - p);
    float num = fmaf(e1, aa, e2 * vt);
    float den = fmaf(e1, bb, e2);
    float sig = 1.f + __expf(-vt);                 // 1/sigmoid(r)
    yt = num * __builtin_amdgcn_rcpf(den * sig);   // wkv * sigmoid(r)
    float ww2 = pp + w;
    float p2  = fmaxf(ww2, kt);
    float e1b = __expf(ww2 - p2), e2b = __expf(kt - p2);
    aa = fmaf(e1b, aa, e2b * vt);
    bb = fmaf(e1b, bb, e2b);
    pp = p2;
}

__global__ __launch_bounds__(64) void wkv_kernel(const float* __restrict__ k,
                                                 const float* __restrict__ v,
                                                 const float* __restrict__ decay,
                                                 const float* __restrict__ first,
                                                 ushort* __restrict__ y) {
    const int T = 1024, E = 1024;
    constexpr int PF = 8;
    int idx = blockIdx.x * 64 + threadIdx.x;
    int b = idx >> 10, e = idx & 1023;
    float w = -expf(decay[e]);
    float u = first[e];
    float aa = 0.f, bb = 0.f, pp = -1e38f;
    const float* kp = k + (size_t)b*T*E + e;
    const float* vp = v + (size_t)b*T*E + e;
    ushort* yp = y + (size_t)b*T*E + e;

    float kbuf[PF], vbuf[PF];
    #pragma unroll
    for (int j = 0; j < PF; j++) {
        kbuf[j] = kp[(size_t)j * E];
        vbuf[j] = vp[(size_t)j * E];
    }
    for (int t0 = 0; t0 < T - PF; t0 += PF) {
        float kn[PF], vn[PF];
        #pragma unroll
        for (int j = 0; j < PF; j++) {
            kn[j] = kp[(size_t)(t0 + PF + j) * E];
            vn[j] = vp[(size_t)(t0 + PF + j) * E];
        }
        #pragma unroll
        for (int j = 0; j < PF; j++) {
            float yt;
            wkv_step(kbuf[j], vbuf[j], w, u, aa, bb, pp, yt);
            yp[(size_t)(t0 + j) * E] = bf16u(yt);
        }
        #pragma unroll
        for (int j = 0; j < PF; j++) { kbuf[j] = kn[j]; vbuf[j] = vn[j]; }
    }
    #pragma unroll
    for (int j = 0; j < PF; j++) {
        float yt;
        wkv_step(kbuf[j], vbuf[j], w, u, aa, bb, pp, yt);
        yp[(size_t)(T - PF + j) * E] = bf16u(yt);
    }
}

extern "C" void kernel_launch(void* const* d_in, const int* in_sizes, int n_in,
                              void* d_out, int out_size, void* d_ws, size_t ws_size,
                              hipStream_t stream) {
    const float* inputs   = (const float*)d_in[0];
    const float* W_in     = (const float*)d_in[1];
    const float* b_in     = (const float*)d_in[2];
    const float* l0_ln0_g = (const float*)d_in[3];
    const float* l0_ln0_b = (const float*)d_in[4];
    const float* l0_ln1_g = (const float*)d_in[5];
    const float* l0_ln1_b = (const float*)d_in[6];
    const float* l0_ln2_g = (const float*)d_in[7];
    const float* l0_ln2_b = (const float*)d_in[8];
    const float* l0_cm_k  = (const float*)d_in[9];
    const float* l0_cm_v  = (const float*)d_in[10];
    const float* l0_cm_r  = (const float*)d_in[11];
    const float* l0_ff_k  = (const float*)d_in[12];
    const float* l0_ff_v  = (const float*)d_in[13];
    const float* l0_ff_r  = (const float*)d_in[14];
    const float* tm_k     = (const float*)d_in[15];
    const float* tm_r     = (const float*)d_in[16];
    const float* tm_o     = (const float*)d_in[17];
    const float* tm_decay = (const float*)d_in[18];
    const float* tm_first = (const float*)d_in[19];
    const float* ln1_g    = (const float*)d_in[20];
    const float* ln1_b    = (const float*)d_in[21];
    const float* ln2_g    = (const float*)d_in[22];
    const float* ln2_b    = (const float*)d_in[23];
    const float* ff_k     = (const float*)d_in[24];
    const float* ff_v     = (const float*)d_in[25];
    const float* ff_r     = (const float*)d_in[26];
    const float* out_g    = (const float*)d_in[27];
    const float* out_b    = (const float*)d_in[28];

    const int Mrows = 4096, E = 1024, E4 = 4096, D = 512, L1 = 11;
    const size_t S = (size_t)Mrows * E;          // 4.19M elems
    char* base = (char*)d_ws;
    float*  res  = (float*) (base);                       // S f32   16.78 MB
    float*  kb   = (float*) (base + S*4);                 // S f32
    float*  rb   = (float*) (base + S*8);                 // S f32
    ushort* xn   = (ushort*)(base + S*12);                // S bf16   8.39 MB
    ushort* yb   = (ushort*)(base + S*14);                // S bf16
    ushort* hb   = (ushort*)(base + S*16);                // 4S bf16 33.55 MB
    ushort* xbf  = (ushort*)(base + S*24);                // M*D bf16 4.19 MB
    ushort* wbuf = (ushort*)(base + S*25);                // 4M bf16  8.39 MB
    (void)ws_size; (void)in_sizes; (void)n_in; (void)out_size;

    dim3 blk(256);
    dim3 gE (E /128, Mrows/128);   // (8,32)
    dim3 gE4(E4/128, Mrows/128);   // (32,32)

    auto cvt = [&](const float* src, ushort* dst, size_t n) {
        int n4 = (int)(n / 4);
        cvt_kernel<<<(n4 + 255) / 256, 256, 0, stream>>>(src, dst, n4);
    };

    // x = inputs @ W_in.T + b_in  -> kb
    cvt(inputs, xbf, (size_t)Mrows * D);
    cvt(W_in, wbuf, (size_t)E * D);
    gemm_bt<0><<<gE, blk, 0, stream>>>(xbf, wbuf, b_in, nullptr, kb, Mrows, E, D);
    // res = LN(x, ln0)
    ln_kernel<float><<<Mrows, blk, 0, stream>>>(kb, l0_ln0_g, l0_ln0_b, res);
    // res += CM(LN(res, ln1); cm_k, cm_v, cm_r)
    ln_kernel<ushort><<<Mrows, blk, 0, stream>>>(res, l0_ln1_g, l0_ln1_b, xn);
    cvt(l0_cm_k, wbuf, (size_t)E4 * E);
    gemm_bt<1><<<gE4, blk, 0, stream>>>(xn, wbuf, nullptr, nullptr, hb, Mrows, E4, E);
    cvt(l0_cm_r, wbuf, (size_t)E * E);
    gemm_bt<0><<<gE,  blk, 0, stream>>>(xn, wbuf, nullptr, nullptr, rb, Mrows, E, E);
    cvt(l0_cm_v, wbuf, (size_t)E * E4);
    gemm_bt<2><<<gE,  blk, 0, stream>>>(hb, wbuf, nullptr, rb, res, Mrows, E, E4);
    // res += CM(LN(res, ln2); ff_k, ff_v, ff_r)   [layer-0 ffn]
    ln_kernel<ushort><<<Mrows, blk, 0, stream>>>(res, l0_ln2_g, l0_ln2_b, xn);
    cvt(l0_ff_k, wbuf, (size_t)E4 * E);
    gemm_bt<1><<<gE4, blk, 0, stream>>>(xn, wbuf, nullptr, nullptr, hb, Mrows, E4, E);
    cvt(l0_ff_r, wbuf, (size_t)E * E);
    gemm_bt<0><<<gE,  blk, 0, stream>>>(xn, wbuf, nullptr, nullptr, rb, Mrows, E, E);
    cvt(l0_ff_v, wbuf, (size_t)E * E4);
    gemm_bt<2><<<gE,  blk, 0, stream>>>(hb, wbuf, nullptr, rb, res, Mrows, E, E4);

    for (int l = 0; l < L1; l++) {
        const float* Wk = tm_k + (size_t)l*E*E;
        const float* Wr = tm_r + (size_t)l*E*E;
        const float* Wo = tm_o + (size_t)l*E*E;
        ln_kernel<ushort><<<Mrows, blk, 0, stream>>>(res, ln1_g + (size_t)l*E, ln1_b + (size_t)l*E, xn);
        cvt(Wk, wbuf, (size_t)E * E);
        gemm_bt<0><<<gE, blk, 0, stream>>>(xn, wbuf, nullptr, nullptr, kb, Mrows, E, E);
        cvt(Wr, wbuf, (size_t)E * E);
        gemm_bt<0><<<gE, blk, 0, stream>>>(xn, wbuf, nullptr, nullptr, rb, Mrows, E, E);
        wkv_kernel<<<64, 64, 0, stream>>>(kb, rb, tm_decay + (size_t)l*E, tm_first + (size_t)l*E, yb);
        cvt(Wo, wbuf, (size_t)E * E);
        gemm_bt<3><<<gE, blk, 0, stream>>>(yb, wbuf, nullptr, nullptr, res, Mrows, E, E);
        ln_kernel<ushort><<<Mrows, blk, 0, stream>>>(res, ln2_g + (size_t)l*E, ln2_b + (size_t)l*E, xn);
        cvt(ff_k + (size_t)l*E4*E, wbuf, (size_t)E4 * E);
        gemm_bt<1><<<gE4, blk, 0, stream>>>(xn, wbuf, nullptr, nullptr, hb, Mrows, E4, E);
        cvt(ff_r + (size_t)l*E*E, wbuf, (size_t)E * E);
        gemm_bt<0><<<gE,  blk, 0, stream>>>(xn, wbuf, nullptr, nullptr, rb, Mrows, E, E);
        cvt(ff_v + (size_t)l*E*E4, wbuf, (size_t)E * E4);
        gemm_bt<2><<<gE,  blk, 0, stream>>>(hb, wbuf, nullptr, rb, res, Mrows, E, E4);
    }

    // out = LN(res, out_g, out_b)
    ln_kernel<float><<<Mrows, blk, 0, stream>>>(res, out_g, out_b, (float*)d_out);
}